// Round 1
// baseline (592.158 us; speedup 1.0000x reference)
//
#include <hip/hip_runtime.h>
#include <hip/hip_bf16.h>

#define LLEN 384
#define CDIM 256
#define NH 8
#define HD 32
#define DIN 128
#define LN_EPS 1e-5f
#define SCL 0.17677669529663687f   // 1/sqrt(32)

typedef __attribute__((ext_vector_type(8))) short bh8;
typedef __attribute__((ext_vector_type(4))) float f32x4;

__device__ __forceinline__ unsigned short f2bf(float f){
  unsigned int u = __float_as_uint(f);
  u += 0x7fffu + ((u >> 16) & 1u);
  return (unsigned short)(u >> 16);
}

// ---------------------------------------------------------------------------
// Pack weights (fp32 row-major [K][N]) into bf16 MFMA B-fragment order:
// P[((kc*16 + c)*64 + lane)*8 + jj] = W[kc*32 + (lane>>4)*8 + jj][c*16 + (lane&15)]
// Matrices: Wpre (K=128), Weq, Wek, Wq, Wk, Wv (K=256), all N=256.
// ---------------------------------------------------------------------------
__global__ __launch_bounds__(256) void pack_w(
    const float* __restrict__ Wpre, const float* __restrict__ Weq,
    const float* __restrict__ Wek,  const float* __restrict__ Wq,
    const float* __restrict__ Wk,   const float* __restrict__ Wv,
    unsigned short* __restrict__ Pp, unsigned short* __restrict__ Pq,
    unsigned short* __restrict__ Pk, unsigned short* __restrict__ PWq,
    unsigned short* __restrict__ PWk, unsigned short* __restrict__ PWv)
{
  int tid = blockIdx.x * 256 + threadIdx.x;   // 176 blocks * 256 = 45056
  const float* W; unsigned short* P; int base;
  if      (tid <  4096){ W = Wpre; P = Pp;  base = tid;         }
  else if (tid < 12288){ W = Weq;  P = Pq;  base = tid -  4096; }
  else if (tid < 20480){ W = Wek;  P = Pk;  base = tid - 12288; }
  else if (tid < 28672){ W = Wq;   P = PWq; base = tid - 20480; }
  else if (tid < 36864){ W = Wk;   P = PWk; base = tid - 28672; }
  else                 { W = Wv;   P = PWv; base = tid - 36864; }
  int l   = base & 63;
  int c   = (base >> 6) & 15;
  int kc  = base >> 10;
  int krow = kc*32 + (l >> 4)*8;
  int col  = c*16 + (l & 15);
  unsigned int wds[4];
  #pragma unroll
  for (int p = 0; p < 4; p++){
    unsigned short lo = f2bf(W[(size_t)(krow + 2*p    )*CDIM + col]);
    unsigned short hi = f2bf(W[(size_t)(krow + 2*p + 1)*CDIM + col]);
    wds[p] = (unsigned int)lo | ((unsigned int)hi << 16);
  }
  uint4 v; v.x = wds[0]; v.y = wds[1]; v.z = wds[2]; v.w = wds[3];
  *(uint4*)(P + (size_t)base*8) = v;
}

// ---------------------------------------------------------------------------
// qkv projections via MFMA: Qm/Km/Vm[j][c] = x3d[j]@W + b   (384x256 each)
// 6 blocks, each handles a 64-row tile, 3 matrices.
// ---------------------------------------------------------------------------
__global__ __launch_bounds__(256) void qkv_mfma(
    const float* __restrict__ x3d,
    const float* __restrict__ bq, const float* __restrict__ bk, const float* __restrict__ bv,
    const unsigned short* __restrict__ PWq, const unsigned short* __restrict__ PWk,
    const unsigned short* __restrict__ PWv,
    float* __restrict__ Qm, float* __restrict__ Km, float* __restrict__ Vm)
{
  __shared__ __align__(16) unsigned short Xb[64*264];
  const int jb = blockIdx.x;          // 0..5
  const int t  = threadIdx.x;
  const int w  = t >> 6, l = t & 63, q4 = l >> 4, lm = l & 15;
  const int wbase = w << 6;

  const float* src = x3d + (size_t)jb*64*CDIM;
  #pragma unroll
  for (int it = 0; it < 16; it++){
    int idx = it*256 + t;             // float4 index over 64x64
    int r = idx >> 6, k4 = (idx & 63) << 2;
    float4 v = *(const float4*)(src + (size_t)r*CDIM + k4);
    ushort4 b;
    b.x = f2bf(v.x); b.y = f2bf(v.y); b.z = f2bf(v.z); b.w = f2bf(v.w);
    *(ushort4*)(&Xb[r*264 + k4]) = b;
  }
  __syncthreads();

  for (int m = 0; m < 3; m++){
    const unsigned short* P = (m == 0) ? PWq : (m == 1) ? PWk : PWv;
    const float* bias       = (m == 0) ? bq  : (m == 1) ? bk  : bv;
    float* Out              = (m == 0) ? Qm  : (m == 1) ? Km  : Vm;
    f32x4 acc[4][4];
    #pragma unroll
    for (int a = 0; a < 4; a++)
      #pragma unroll
      for (int b = 0; b < 4; b++){ f32x4 z = {0.f,0.f,0.f,0.f}; acc[a][b] = z; }
    #pragma unroll
    for (int kc = 0; kc < 8; kc++){
      bh8 af[4];
      #pragma unroll
      for (int rt = 0; rt < 4; rt++)
        af[rt] = *(const bh8*)(&Xb[(rt*16 + lm)*264 + kc*32 + q4*8]);
      #pragma unroll
      for (int ct = 0; ct < 4; ct++){
        bh8 bf = *(const bh8*)(P + ((size_t)(kc*16 + (w*4 + ct))*64 + l)*8);
        #pragma unroll
        for (int rt = 0; rt < 4; rt++)
          acc[rt][ct] = __builtin_amdgcn_mfma_f32_16x16x32_bf16(af[rt], bf, acc[rt][ct], 0, 0, 0);
      }
    }
    #pragma unroll
    for (int ct = 0; ct < 4; ct++){
      int c = wbase + ct*16 + lm;
      float bb = bias[c];
      #pragma unroll
      for (int rt = 0; rt < 4; rt++)
        #pragma unroll
        for (int rg = 0; rg < 4; rg++){
          int row = jb*64 + rt*16 + q4*4 + rg;
          Out[(size_t)row*CDIM + c] = acc[rt][ct][rg] + bb;
        }
    }
  }
}

// ---------------------------------------------------------------------------
// Main fused kernel: one block per query position i.
// ---------------------------------------------------------------------------
__global__ __launch_bounds__(256, 2) void x3d_attn(
  const float* __restrict__ x2d,
  const float* __restrict__ bpre, const float* __restrict__ ln_g, const float* __restrict__ ln_b,
  const float* __restrict__ beq,  const float* __restrict__ bek,
  const float* __restrict__ Wo,   const float* __restrict__ bo,
  const float* __restrict__ Qm,   const float* __restrict__ Km, const float* __restrict__ Vm,
  const unsigned short* __restrict__ Pp, const unsigned short* __restrict__ Pq,
  const unsigned short* __restrict__ Pk,
  float* __restrict__ out)
{
  // EX aliases X-tile (stride 136, bf16) during GEMM1 and E-tile (stride 264,
  // bf16) for GEMM2/3 — phases are separated by barriers.
  __shared__ __align__(16) unsigned short EX[64*264];      // 33792 B
  __shared__ float scoresS[NH*LLEN];                       // 12288 B
  __shared__ float rowstat[4][64][2];                      //  2048 B
  __shared__ float muS[64], istdS[64];                     //   512 B
  __shared__ float qiS[CDIM];                              //  1024 B
  __shared__ float bpreS[CDIM], gS[CDIM], bSh[CDIM], beqS[CDIM], bekS[CDIM]; // 5120 B
  __shared__ float x2buf[CDIM], xoutS[CDIM];               //  2048 B

  const int i = blockIdx.x;
  const int t = threadIdx.x;
  const int w = t >> 6, l = t & 63, q4 = l >> 4, lm = l & 15;
  const int wbase = w << 6;

  qiS[t]   = Qm[i*CDIM + t];
  bpreS[t] = bpre[t]; gS[t] = ln_g[t]; bSh[t] = ln_b[t];
  beqS[t]  = beq[t];  bekS[t] = bek[t];

  float x2p[4] = {0.f, 0.f, 0.f, 0.f};

  for (int j0 = 0; j0 < LLEN; j0 += 64) {
    __syncthreads();                       // EX free for re-staging
    // ---- stage x2d tile (64 x 128) as bf16, stride 136 ----
    {
      const float* src = x2d + ((size_t)i*LLEN + j0)*DIN;
      #pragma unroll
      for (int it = 0; it < 8; it++){
        int r  = it*8 + (t >> 5);
        int k4 = (t & 31)*4;
        float4 v = *(const float4*)(src + (size_t)r*DIN + k4);
        ushort4 b;
        b.x = f2bf(v.x); b.y = f2bf(v.y); b.z = f2bf(v.z); b.w = f2bf(v.w);
        *(ushort4*)(&EX[r*136 + k4]) = b;
      }
    }
    __syncthreads();

    // ---- GEMM1: Epre = X @ Wpre ----
    f32x4 acc[4][4];
    #pragma unroll
    for (int a = 0; a < 4; a++)
      #pragma unroll
      for (int b = 0; b < 4; b++){ f32x4 z = {0.f,0.f,0.f,0.f}; acc[a][b] = z; }
    #pragma unroll
    for (int kc = 0; kc < 4; kc++){
      bh8 af[4];
      #pragma unroll
      for (int rt = 0; rt < 4; rt++)
        af[rt] = *(const bh8*)(&EX[(rt*16 + lm)*136 + kc*32 + q4*8]);
      #pragma unroll
      for (int ct = 0; ct < 4; ct++){
        bh8 bf = *(const bh8*)(Pp + ((size_t)(kc*16 + (w*4 + ct))*64 + l)*8);
        #pragma unroll
        for (int rt = 0; rt < 4; rt++)
          acc[rt][ct] = __builtin_amdgcn_mfma_f32_16x16x32_bf16(af[rt], bf, acc[rt][ct], 0, 0, 0);
      }
    }

    // ---- + bpre, per-row LN stats (quad butterfly -> LDS) ----
    #pragma unroll
    for (int rt = 0; rt < 4; rt++){
      float psum[4] = {0,0,0,0}, psq[4] = {0,0,0,0};
      #pragma unroll
      for (int ct = 0; ct < 4; ct++){
        float bb = bpreS[wbase + ct*16 + lm];
        #pragma unroll
        for (int rg = 0; rg < 4; rg++){
          float v = acc[rt][ct][rg] + bb;
          acc[rt][ct][rg] = v;
          psum[rg] += v; psq[rg] += v*v;
        }
      }
      #pragma unroll
      for (int rg = 0; rg < 4; rg++){
        float s = psum[rg], s2 = psq[rg];
        #pragma unroll
        for (int mk = 1; mk < 16; mk <<= 1){
          s  += __shfl_xor(s,  mk, 64);
          s2 += __shfl_xor(s2, mk, 64);
        }
        if (lm == 0){
          int row = rt*16 + q4*4 + rg;
          rowstat[w][row][0] = s;
          rowstat[w][row][1] = s2;
        }
      }
    }
    __syncthreads();
    if (t < 64){
      float s  = rowstat[0][t][0] + rowstat[1][t][0] + rowstat[2][t][0] + rowstat[3][t][0];
      float s2 = rowstat[0][t][1] + rowstat[1][t][1] + rowstat[2][t][1] + rowstat[3][t][1];
      float mu = s * (1.f/256.f);
      float var = s2 * (1.f/256.f) - mu*mu;
      muS[t] = mu;
      istdS[t] = rsqrtf(var + LN_EPS);
    }
    __syncthreads();

    // ---- LN + ReLU -> bf16 E tile (stride 264) ----
    #pragma unroll
    for (int rt = 0; rt < 4; rt++){
      #pragma unroll
      for (int rg = 0; rg < 4; rg++){
        int row = rt*16 + q4*4 + rg;
        float mu = muS[row], is = istdS[row];
        #pragma unroll
        for (int ct = 0; ct < 4; ct++){
          int c = wbase + ct*16 + lm;
          float v = (acc[rt][ct][rg] - mu)*is*gS[c] + bSh[c];
          v = fmaxf(v, 0.f);
          EX[row*264 + c] = f2bf(v);
        }
      }
    }
    __syncthreads();

    // ---- GEMM2: EFK = E @ Wek ----
    #pragma unroll
    for (int a = 0; a < 4; a++)
      #pragma unroll
      for (int b = 0; b < 4; b++){ f32x4 z = {0.f,0.f,0.f,0.f}; acc[a][b] = z; }
    #pragma unroll
    for (int kc = 0; kc < 8; kc++){
      bh8 af[4];
      #pragma unroll
      for (int rt = 0; rt < 4; rt++)
        af[rt] = *(const bh8*)(&EX[(rt*16 + lm)*264 + kc*32 + q4*8]);
      #pragma unroll
      for (int ct = 0; ct < 4; ct++){
        bh8 bf = *(const bh8*)(Pk + ((size_t)(kc*16 + (w*4 + ct))*64 + l)*8);
        #pragma unroll
        for (int rt = 0; rt < 4; rt++)
          acc[rt][ct] = __builtin_amdgcn_mfma_f32_16x16x32_bf16(af[rt], bf, acc[rt][ct], 0, 0, 0);
      }
    }

    // ---- scores[h][j] = (qi.k_j + efk[i,j,h,:].q_j) * SCALE ----
    float sreg[4][4][2];
    #pragma unroll
    for (int rt = 0; rt < 4; rt++){
      #pragma unroll
      for (int rg = 0; rg < 4; rg++){
        int j = j0 + rt*16 + q4*4 + rg;
        float t01 = 0.f, t23 = 0.f;
        #pragma unroll
        for (int ct = 0; ct < 4; ct++){
          int c = wbase + ct*16 + lm;
          float efk = acc[rt][ct][rg] + bekS[c];
          float contrib = efk * Qm[(size_t)j*CDIM + c] + qiS[c] * Km[(size_t)j*CDIM + c];
          if (ct < 2) t01 += contrib; else t23 += contrib;
        }
        #pragma unroll
        for (int mk = 1; mk < 16; mk <<= 1){
          t01 += __shfl_xor(t01, mk, 64);
          t23 += __shfl_xor(t23, mk, 64);
        }
        t01 *= SCL; t23 *= SCL;
        sreg[rt][rg][0] = t01;
        sreg[rt][rg][1] = t23;
        if (lm == 0){
          scoresS[(2*w    )*LLEN + j] = t01;
          scoresS[(2*w + 1)*LLEN + j] = t23;
        }
      }
    }

    // ---- GEMM3: EFQ = E @ Weq ----
    #pragma unroll
    for (int a = 0; a < 4; a++)
      #pragma unroll
      for (int b = 0; b < 4; b++){ f32x4 z = {0.f,0.f,0.f,0.f}; acc[a][b] = z; }
    #pragma unroll
    for (int kc = 0; kc < 8; kc++){
      bh8 af[4];
      #pragma unroll
      for (int rt = 0; rt < 4; rt++)
        af[rt] = *(const bh8*)(&EX[(rt*16 + lm)*264 + kc*32 + q4*8]);
      #pragma unroll
      for (int ct = 0; ct < 4; ct++){
        bh8 bf = *(const bh8*)(Pq + ((size_t)(kc*16 + (w*4 + ct))*64 + l)*8);
        #pragma unroll
        for (int rt = 0; rt < 4; rt++)
          acc[rt][ct] = __builtin_amdgcn_mfma_f32_16x16x32_bf16(af[rt], bf, acc[rt][ct], 0, 0, 0);
      }
    }

    // ---- online x2: x2[h,i,c] += scores[h,j] * efq[j,c] (pre-softmax!) ----
    #pragma unroll
    for (int ct = 0; ct < 4; ct++){
      int c = wbase + ct*16 + lm;
      float bq_ = beqS[c];
      float p = 0.f;
      #pragma unroll
      for (int rt = 0; rt < 4; rt++)
        #pragma unroll
        for (int rg = 0; rg < 4; rg++)
          p += sreg[rt][rg][ct >> 1] * (acc[rt][ct][rg] + bq_);
      x2p[ct] += p;
    }
  } // j-tile loop

  __syncthreads();

  // ---- x2 cross-quad reduce ----
  #pragma unroll
  for (int ct = 0; ct < 4; ct++){
    float v = x2p[ct];
    v += __shfl_xor(v, 16, 64);
    v += __shfl_xor(v, 32, 64);
    if (l < 16) x2buf[wbase + ct*16 + l] = v;
  }

  // ---- softmax per head (32 threads / head) ----
  const int h = t >> 5;
  const int g32 = t & 31;
  float sv[12];
  float mx = -3.0e38f;
  #pragma unroll
  for (int it = 0; it < 12; it++){
    float s = scoresS[h*LLEN + it*32 + g32];
    sv[it] = s;
    mx = fmaxf(mx, s);
  }
  #pragma unroll
  for (int mk = 1; mk < 32; mk <<= 1) mx = fmaxf(mx, __shfl_xor(mx, mk, 64));
  float den = 0.f;
  #pragma unroll
  for (int it = 0; it < 12; it++){ float e = __expf(sv[it] - mx); sv[it] = e; den += e; }
  #pragma unroll
  for (int mk = 1; mk < 32; mk <<= 1) den += __shfl_xor(den, mk, 64);
  float rden = 1.f / den;
  #pragma unroll
  for (int it = 0; it < 12; it++) scoresS[h*LLEN + it*32 + g32] = sv[it]*rden;
  __syncthreads();

  // ---- x1[c=t] = sum_j w[h,j]*V[j,c]; combine; out-proj ----
  float x1 = 0.f;
  {
    const float* vp = Vm + t;
    #pragma unroll 16
    for (int j = 0; j < LLEN; j++)
      x1 = fmaf(scoresS[h*LLEN + j], vp[(size_t)j*CDIM], x1);
  }
  xoutS[t] = x1 + x2buf[t];
  __syncthreads();

  float acco = bo[t];
  #pragma unroll 8
  for (int c = 0; c < CDIM; c++)
    acco = fmaf(xoutS[c], Wo[(size_t)c*CDIM + t], acco);
  out[(size_t)i*CDIM + t] = acco;
}

// ---------------------------------------------------------------------------
extern "C" void kernel_launch(void* const* d_in, const int* in_sizes, int n_in,
                              void* d_out, int out_size, void* d_ws, size_t ws_size,
                              hipStream_t stream)
{
  const float* x2d  = (const float*)d_in[0];
  const float* x3d  = (const float*)d_in[1];
  const float* Wq   = (const float*)d_in[2];
  const float* bq   = (const float*)d_in[3];
  const float* Wk   = (const float*)d_in[4];
  const float* bk   = (const float*)d_in[5];
  const float* Wv   = (const float*)d_in[6];
  const float* bv   = (const float*)d_in[7];
  const float* Wpre = (const float*)d_in[8];
  const float* bpre = (const float*)d_in[9];
  const float* ln_g = (const float*)d_in[10];
  const float* ln_b = (const float*)d_in[11];
  const float* Weq  = (const float*)d_in[12];
  const float* beq  = (const float*)d_in[13];
  const float* Wek  = (const float*)d_in[14];
  const float* bek  = (const float*)d_in[15];
  const float* Wo   = (const float*)d_in[16];
  const float* bo   = (const float*)d_in[17];
  float* out = (float*)d_out;

  float* Qm = (float*)d_ws;
  float* Km = Qm + LLEN*CDIM;
  float* Vm = Km + LLEN*CDIM;
  unsigned short* Pp  = (unsigned short*)(Vm + LLEN*CDIM);
  unsigned short* Pq  = Pp  + DIN*CDIM;
  unsigned short* Pk  = Pq  + CDIM*CDIM;
  unsigned short* PWq = Pk  + CDIM*CDIM;
  unsigned short* PWk = PWq + CDIM*CDIM;
  unsigned short* PWv = PWk + CDIM*CDIM;

  pack_w<<<dim3(176), dim3(256), 0, stream>>>(Wpre, Weq, Wek, Wq, Wk, Wv,
                                              Pp, Pq, Pk, PWq, PWk, PWv);
  qkv_mfma<<<dim3(6), dim3(256), 0, stream>>>(x3d, bq, bk, bv, PWq, PWk, PWv,
                                              Qm, Km, Vm);
  x3d_attn<<<dim3(LLEN), dim3(256), 0, stream>>>(x2d, bpre, ln_g, ln_b, beq, bek,
                                                 Wo, bo, Qm, Km, Vm, Pp, Pq, Pk, out);
}

// Round 2
// 264.276 us; speedup vs baseline: 2.2407x; 2.2407x over previous
//
#include <hip/hip_runtime.h>
#include <hip/hip_bf16.h>

#define LLEN 384
#define CDIM 256
#define NH 8
#define HD 32
#define DIN 128
#define LN_EPS 1e-5f
#define SCL 0.17677669529663687f   // 1/sqrt(32)

typedef __attribute__((ext_vector_type(8))) short bh8;
typedef __attribute__((ext_vector_type(4))) float f32x4;
typedef __attribute__((ext_vector_type(4))) unsigned int u32x4;

__device__ __forceinline__ unsigned short f2bf(float f){
  unsigned int u = __float_as_uint(f);
  u += 0x7fffu + ((u >> 16) & 1u);
  return (unsigned short)(u >> 16);
}

// ---------------------------------------------------------------------------
// Pack weights (fp32 row-major [K][N]) into bf16 MFMA B-fragment order:
// P[((kc*16 + c)*64 + lane)*8 + jj] = W[kc*32 + (lane>>4)*8 + jj][c*16 + (lane&15)]
// ---------------------------------------------------------------------------
__global__ __launch_bounds__(256) void pack_w(
    const float* __restrict__ Wpre, const float* __restrict__ Weq,
    const float* __restrict__ Wek,  const float* __restrict__ Wq,
    const float* __restrict__ Wk,   const float* __restrict__ Wv,
    unsigned short* __restrict__ Pp, unsigned short* __restrict__ Pq,
    unsigned short* __restrict__ Pk, unsigned short* __restrict__ PWq,
    unsigned short* __restrict__ PWk, unsigned short* __restrict__ PWv)
{
  int tid = blockIdx.x * 256 + threadIdx.x;   // 176 blocks * 256 = 45056
  const float* W; unsigned short* P; int base;
  if      (tid <  4096){ W = Wpre; P = Pp;  base = tid;         }
  else if (tid < 12288){ W = Weq;  P = Pq;  base = tid -  4096; }
  else if (tid < 20480){ W = Wek;  P = Pk;  base = tid - 12288; }
  else if (tid < 28672){ W = Wq;   P = PWq; base = tid - 20480; }
  else if (tid < 36864){ W = Wk;   P = PWk; base = tid - 28672; }
  else                 { W = Wv;   P = PWv; base = tid - 36864; }
  int l   = base & 63;
  int c   = (base >> 6) & 15;
  int kc  = base >> 10;
  int krow = kc*32 + (l >> 4)*8;
  int col  = c*16 + (l & 15);
  unsigned int wds[4];
  #pragma unroll
  for (int p = 0; p < 4; p++){
    unsigned short lo = f2bf(W[(size_t)(krow + 2*p    )*CDIM + col]);
    unsigned short hi = f2bf(W[(size_t)(krow + 2*p + 1)*CDIM + col]);
    wds[p] = (unsigned int)lo | ((unsigned int)hi << 16);
  }
  uint4 v; v.x = wds[0]; v.y = wds[1]; v.z = wds[2]; v.w = wds[3];
  *(uint4*)(P + (size_t)base*8) = v;
}

// ---------------------------------------------------------------------------
// qkv: Qm(f32)+QmH(bf16), KmH(bf16), Vm(f32). 6 blocks x 64 rows.
// ---------------------------------------------------------------------------
__global__ __launch_bounds__(256) void qkv_mfma(
    const float* __restrict__ x3d,
    const float* __restrict__ bq, const float* __restrict__ bk, const float* __restrict__ bv,
    const unsigned short* __restrict__ PWq, const unsigned short* __restrict__ PWk,
    const unsigned short* __restrict__ PWv,
    float* __restrict__ Qm, float* __restrict__ Vm,
    unsigned short* __restrict__ QmH, unsigned short* __restrict__ KmH)
{
  __shared__ __align__(16) unsigned short Xb[64*264];
  const int jb = blockIdx.x;          // 0..5
  const int t  = threadIdx.x;
  const int w  = t >> 6, l = t & 63, q4 = l >> 4, lm = l & 15;
  const int wbase = w << 6;

  const float* src = x3d + (size_t)jb*64*CDIM;
  #pragma unroll
  for (int it = 0; it < 16; it++){
    int idx = it*256 + t;             // float4 index over 64x64
    int r = idx >> 6, k4 = (idx & 63) << 2;
    float4 v = *(const float4*)(src + (size_t)r*CDIM + k4);
    ushort4 b;
    b.x = f2bf(v.x); b.y = f2bf(v.y); b.z = f2bf(v.z); b.w = f2bf(v.w);
    *(ushort4*)(&Xb[r*264 + k4]) = b;
  }
  __syncthreads();

  for (int m = 0; m < 3; m++){
    const unsigned short* P = (m == 0) ? PWq : (m == 1) ? PWk : PWv;
    const float* bias       = (m == 0) ? bq  : (m == 1) ? bk  : bv;
    f32x4 acc[4][4];
    #pragma unroll
    for (int a = 0; a < 4; a++)
      #pragma unroll
      for (int b = 0; b < 4; b++){ f32x4 z = {0.f,0.f,0.f,0.f}; acc[a][b] = z; }
    #pragma unroll
    for (int kc = 0; kc < 8; kc++){
      bh8 af[4];
      #pragma unroll
      for (int rt = 0; rt < 4; rt++)
        af[rt] = *(const bh8*)(&Xb[(rt*16 + lm)*264 + kc*32 + q4*8]);
      #pragma unroll
      for (int ct = 0; ct < 4; ct++){
        bh8 bf = *(const bh8*)(P + ((size_t)(kc*16 + (w*4 + ct))*64 + l)*8);
        #pragma unroll
        for (int rt = 0; rt < 4; rt++)
          acc[rt][ct] = __builtin_amdgcn_mfma_f32_16x16x32_bf16(af[rt], bf, acc[rt][ct], 0, 0, 0);
      }
    }
    #pragma unroll
    for (int ct = 0; ct < 4; ct++){
      int c = wbase + ct*16 + lm;
      float bb = bias[c];
      #pragma unroll
      for (int rt = 0; rt < 4; rt++)
        #pragma unroll
        for (int rg = 0; rg < 4; rg++){
          int row = jb*64 + rt*16 + q4*4 + rg;
          float v = acc[rt][ct][rg] + bb;
          if (m == 0){
            Qm[(size_t)row*CDIM + c] = v;
            QmH[(size_t)row*CDIM + c] = f2bf(v);
          } else if (m == 1){
            KmH[(size_t)row*CDIM + c] = f2bf(v);
          } else {
            Vm[(size_t)row*CDIM + c] = v;
          }
        }
    }
  }
}

// ---------------------------------------------------------------------------
// qk_dots: Sg[i][h][j] = q[h,i,:].k[h,j,:]  (unscaled). 36 blocks of 64x64.
// ---------------------------------------------------------------------------
__global__ __launch_bounds__(256) void qk_dots(
    const unsigned short* __restrict__ QmH, const unsigned short* __restrict__ KmH,
    float* __restrict__ Sg)
{
  const int bx = blockIdx.x;
  const int i0 = (bx / 6) * 64, j0 = (bx % 6) * 64;
  const int t = threadIdx.x;
  const int w = t >> 6, l = t & 63, q4 = l >> 4, lm = l & 15;

  #pragma unroll
  for (int hh = 0; hh < 2; hh++){
    int h = w*2 + hh;
    bh8 a[4], b[4];
    #pragma unroll
    for (int rt = 0; rt < 4; rt++)
      a[rt] = *(const bh8*)(QmH + (size_t)(i0 + rt*16 + lm)*CDIM + h*HD + q4*8);
    #pragma unroll
    for (int ct = 0; ct < 4; ct++)
      b[ct] = *(const bh8*)(KmH + (size_t)(j0 + ct*16 + lm)*CDIM + h*HD + q4*8);
    #pragma unroll
    for (int rt = 0; rt < 4; rt++)
      #pragma unroll
      for (int ct = 0; ct < 4; ct++){
        f32x4 z = {0.f,0.f,0.f,0.f};
        f32x4 acc = __builtin_amdgcn_mfma_f32_16x16x32_bf16(a[rt], b[ct], z, 0, 0, 0);
        #pragma unroll
        for (int rg = 0; rg < 4; rg++){
          int i = i0 + rt*16 + q4*4 + rg;
          int j = j0 + ct*16 + lm;
          Sg[((size_t)i*NH + h)*LLEN + j] = acc[rg];
        }
      }
  }
}

// ---------------------------------------------------------------------------
// Main tile kernel: one block per (i, j-tile). 2304 blocks.
// Reads Sg (qk term), writes final scaled scores back to Sg, x2 partials.
// ---------------------------------------------------------------------------
__global__ __launch_bounds__(256, 3) void x3d_tiles(
  const float* __restrict__ x2d,
  const float* __restrict__ bpre, const float* __restrict__ ln_g, const float* __restrict__ ln_b,
  const float* __restrict__ beq,  const float* __restrict__ bek,
  const float* __restrict__ Qm,
  const unsigned short* __restrict__ Pp, const unsigned short* __restrict__ Pq,
  const unsigned short* __restrict__ Pk,
  float* __restrict__ Sg, float* __restrict__ x2part)
{
  __shared__ __align__(16) unsigned short EX[64*264];      // 33792 B (X stride136 / E stride264)
  __shared__ float rowstat[4][64][2];                      //  2048 B
  __shared__ float muS[64], istdS[64];                     //   512 B
  __shared__ float bpreS[CDIM], gS[CDIM], bSh[CDIM], beqS[CDIM], bekS[CDIM]; // 5120 B

  const int bx = blockIdx.x;
  const int i = bx / 6, jt = bx % 6, j0 = jt * 64;
  const int t = threadIdx.x;
  const int w = t >> 6, l = t & 63, q4 = l >> 4, lm = l & 15;
  const int wbase = w << 6;

  bpreS[t] = bpre[t]; gS[t] = ln_g[t]; bSh[t] = ln_b[t];
  beqS[t]  = beq[t];  bekS[t] = bek[t];

  // ---- stage x2d tile (64 x 128) as bf16, stride 136; non-temporal so the
  // 75 MB stream doesn't evict the packed weights from L2 ----
  {
    const float* src = x2d + ((size_t)i*LLEN + j0)*DIN;
    #pragma unroll
    for (int it = 0; it < 8; it++){
      int r  = it*8 + (t >> 5);
      int k4 = (t & 31)*4;
      u32x4 uv = __builtin_nontemporal_load((const u32x4*)(src + (size_t)r*DIN + k4));
      ushort4 b;
      b.x = f2bf(__uint_as_float(uv.x)); b.y = f2bf(__uint_as_float(uv.y));
      b.z = f2bf(__uint_as_float(uv.z)); b.w = f2bf(__uint_as_float(uv.w));
      *(ushort4*)(&EX[r*136 + k4]) = b;
    }
  }
  __syncthreads();

  // ---- GEMM1: Epre = X @ Wpre ----
  f32x4 acc[4][4];
  #pragma unroll
  for (int a = 0; a < 4; a++)
    #pragma unroll
    for (int b = 0; b < 4; b++){ f32x4 z = {0.f,0.f,0.f,0.f}; acc[a][b] = z; }
  #pragma unroll
  for (int kc = 0; kc < 4; kc++){
    bh8 af[4];
    #pragma unroll
    for (int rt = 0; rt < 4; rt++)
      af[rt] = *(const bh8*)(&EX[(rt*16 + lm)*136 + kc*32 + q4*8]);
    #pragma unroll
    for (int ct = 0; ct < 4; ct++){
      bh8 bf = *(const bh8*)(Pp + ((size_t)(kc*16 + (w*4 + ct))*64 + l)*8);
      #pragma unroll
      for (int rt = 0; rt < 4; rt++)
        acc[rt][ct] = __builtin_amdgcn_mfma_f32_16x16x32_bf16(af[rt], bf, acc[rt][ct], 0, 0, 0);
    }
  }

  // ---- + bpre, per-row LN stats ----
  #pragma unroll
  for (int rt = 0; rt < 4; rt++){
    float psum[4] = {0,0,0,0}, psq[4] = {0,0,0,0};
    #pragma unroll
    for (int ct = 0; ct < 4; ct++){
      float bb = bpreS[wbase + ct*16 + lm];
      #pragma unroll
      for (int rg = 0; rg < 4; rg++){
        float v = acc[rt][ct][rg] + bb;
        acc[rt][ct][rg] = v;
        psum[rg] += v; psq[rg] += v*v;
      }
    }
    #pragma unroll
    for (int rg = 0; rg < 4; rg++){
      float s = psum[rg], s2 = psq[rg];
      #pragma unroll
      for (int mk = 1; mk < 16; mk <<= 1){
        s  += __shfl_xor(s,  mk, 64);
        s2 += __shfl_xor(s2, mk, 64);
      }
      if (lm == 0){
        int row = rt*16 + q4*4 + rg;
        rowstat[w][row][0] = s;
        rowstat[w][row][1] = s2;
      }
    }
  }
  __syncthreads();
  if (t < 64){
    float s  = rowstat[0][t][0] + rowstat[1][t][0] + rowstat[2][t][0] + rowstat[3][t][0];
    float s2 = rowstat[0][t][1] + rowstat[1][t][1] + rowstat[2][t][1] + rowstat[3][t][1];
    float mu = s * (1.f/256.f);
    float var = s2 * (1.f/256.f) - mu*mu;
    muS[t] = mu;
    istdS[t] = rsqrtf(var + LN_EPS);
  }
  __syncthreads();

  // ---- LN + ReLU -> bf16 E tile (stride 264) ----
  #pragma unroll
  for (int rt = 0; rt < 4; rt++){
    #pragma unroll
    for (int rg = 0; rg < 4; rg++){
      int row = rt*16 + q4*4 + rg;
      float mu = muS[row], is = istdS[row];
      #pragma unroll
      for (int ct = 0; ct < 4; ct++){
        int c = wbase + ct*16 + lm;
        float v = (acc[rt][ct][rg] - mu)*is*gS[c] + bSh[c];
        v = fmaxf(v, 0.f);
        EX[row*264 + c] = f2bf(v);
      }
    }
  }
  __syncthreads();

  // ---- GEMM2: EFK = E @ Wek ----
  #pragma unroll
  for (int a = 0; a < 4; a++)
    #pragma unroll
    for (int b = 0; b < 4; b++){ f32x4 z = {0.f,0.f,0.f,0.f}; acc[a][b] = z; }
  #pragma unroll
  for (int kc = 0; kc < 8; kc++){
    bh8 af[4];
    #pragma unroll
    for (int rt = 0; rt < 4; rt++)
      af[rt] = *(const bh8*)(&EX[(rt*16 + lm)*264 + kc*32 + q4*8]);
    #pragma unroll
    for (int ct = 0; ct < 4; ct++){
      bh8 bf = *(const bh8*)(Pk + ((size_t)(kc*16 + (w*4 + ct))*64 + l)*8);
      #pragma unroll
      for (int rt = 0; rt < 4; rt++)
        acc[rt][ct] = __builtin_amdgcn_mfma_f32_16x16x32_bf16(af[rt], bf, acc[rt][ct], 0, 0, 0);
    }
  }

  // ---- scores: term2 reduce + precomputed qk term + scale ----
  float sreg[4][4][2];
  #pragma unroll
  for (int rt = 0; rt < 4; rt++){
    #pragma unroll
    for (int rg = 0; rg < 4; rg++){
      int j = j0 + rt*16 + q4*4 + rg;
      float t01 = 0.f, t23 = 0.f;
      #pragma unroll
      for (int ct = 0; ct < 4; ct++){
        int c = wbase + ct*16 + lm;
        float efk = acc[rt][ct][rg] + bekS[c];
        float contrib = efk * Qm[(size_t)j*CDIM + c];
        if (ct < 2) t01 += contrib; else t23 += contrib;
      }
      #pragma unroll
      for (int mk = 1; mk < 16; mk <<= 1){
        t01 += __shfl_xor(t01, mk, 64);
        t23 += __shfl_xor(t23, mk, 64);
      }
      int h0 = 2*w, h1 = 2*w + 1;
      float s0 = (t01 + Sg[((size_t)i*NH + h0)*LLEN + j]) * SCL;
      float s1 = (t23 + Sg[((size_t)i*NH + h1)*LLEN + j]) * SCL;
      sreg[rt][rg][0] = s0;
      sreg[rt][rg][1] = s1;
      if (lm == 0){
        Sg[((size_t)i*NH + h0)*LLEN + j] = s0;
        Sg[((size_t)i*NH + h1)*LLEN + j] = s1;
      }
    }
  }

  // ---- GEMM3: EFQ = E @ Weq ----
  #pragma unroll
  for (int a = 0; a < 4; a++)
    #pragma unroll
    for (int b = 0; b < 4; b++){ f32x4 z = {0.f,0.f,0.f,0.f}; acc[a][b] = z; }
  #pragma unroll
  for (int kc = 0; kc < 8; kc++){
    bh8 af[4];
    #pragma unroll
    for (int rt = 0; rt < 4; rt++)
      af[rt] = *(const bh8*)(&EX[(rt*16 + lm)*264 + kc*32 + q4*8]);
    #pragma unroll
    for (int ct = 0; ct < 4; ct++){
      bh8 bf = *(const bh8*)(Pq + ((size_t)(kc*16 + (w*4 + ct))*64 + l)*8);
      #pragma unroll
      for (int rt = 0; rt < 4; rt++)
        acc[rt][ct] = __builtin_amdgcn_mfma_f32_16x16x32_bf16(af[rt], bf, acc[rt][ct], 0, 0, 0);
    }
  }

  // ---- x2 partial: x2[h,c] += scores[h,j]*efq[j,c] (pre-softmax scaled) ----
  #pragma unroll
  for (int ct = 0; ct < 4; ct++){
    int c = wbase + ct*16 + lm;
    float bq_ = beqS[c];
    float p = 0.f;
    #pragma unroll
    for (int rt = 0; rt < 4; rt++)
      #pragma unroll
      for (int rg = 0; rg < 4; rg++)
        p += sreg[rt][rg][ct >> 1] * (acc[rt][ct][rg] + bq_);
    // cross-quad reduce: quads hold partial sums over their j subset
    p += __shfl_xor(p, 16, 64);
    p += __shfl_xor(p, 32, 64);
    if (l < 16)
      x2part[((size_t)jt*LLEN + i)*CDIM + wbase + ct*16 + l] = p;
  }
}

// ---------------------------------------------------------------------------
// finish: softmax + x1 + x2 + out-proj. 384 blocks.
// ---------------------------------------------------------------------------
__global__ __launch_bounds__(256) void finish(
    const float* __restrict__ Sg, const float* __restrict__ x2part,
    const float* __restrict__ Vm, const float* __restrict__ Wo,
    const float* __restrict__ bo, float* __restrict__ out)
{
  __shared__ float scoresS[NH*LLEN];   // 12 KB
  __shared__ float xoutS[CDIM];
  const int i = blockIdx.x;
  const int t = threadIdx.x;

  #pragma unroll
  for (int it = 0; it < 12; it++)
    scoresS[it*256 + t] = Sg[(size_t)i*NH*LLEN + it*256 + t];
  __syncthreads();

  const int h = t >> 5;
  const int g32 = t & 31;
  float sv[12];
  float mx = -3.0e38f;
  #pragma unroll
  for (int it = 0; it < 12; it++){
    float s = scoresS[h*LLEN + it*32 + g32];
    sv[it] = s;
    mx = fmaxf(mx, s);
  }
  #pragma unroll
  for (int mk = 1; mk < 32; mk <<= 1) mx = fmaxf(mx, __shfl_xor(mx, mk, 64));
  float den = 0.f;
  #pragma unroll
  for (int it = 0; it < 12; it++){ float e = __expf(sv[it] - mx); sv[it] = e; den += e; }
  #pragma unroll
  for (int mk = 1; mk < 32; mk <<= 1) den += __shfl_xor(den, mk, 64);
  float rden = 1.f / den;
  #pragma unroll
  for (int it = 0; it < 12; it++) scoresS[h*LLEN + it*32 + g32] = sv[it]*rden;
  __syncthreads();

  float x1 = 0.f;
  {
    const float* vp = Vm + t;
    #pragma unroll 16
    for (int j = 0; j < LLEN; j++)
      x1 = fmaf(scoresS[h*LLEN + j], vp[(size_t)j*CDIM], x1);
  }
  float x2v = 0.f;
  #pragma unroll
  for (int jt = 0; jt < 6; jt++)
    x2v += x2part[((size_t)jt*LLEN + i)*CDIM + t];
  xoutS[t] = x1 + x2v;
  __syncthreads();

  float acco = bo[t];
  #pragma unroll 8
  for (int c = 0; c < CDIM; c++)
    acco = fmaf(xoutS[c], Wo[(size_t)c*CDIM + t], acco);
  out[(size_t)i*CDIM + t] = acco;
}

// ---------------------------------------------------------------------------
extern "C" void kernel_launch(void* const* d_in, const int* in_sizes, int n_in,
                              void* d_out, int out_size, void* d_ws, size_t ws_size,
                              hipStream_t stream)
{
  const float* x2d  = (const float*)d_in[0];
  const float* x3d  = (const float*)d_in[1];
  const float* Wq   = (const float*)d_in[2];
  const float* bq   = (const float*)d_in[3];
  const float* Wk   = (const float*)d_in[4];
  const float* bk   = (const float*)d_in[5];
  const float* Wv   = (const float*)d_in[6];
  const float* bv   = (const float*)d_in[7];
  const float* Wpre = (const float*)d_in[8];
  const float* bpre = (const float*)d_in[9];
  const float* ln_g = (const float*)d_in[10];
  const float* ln_b = (const float*)d_in[11];
  const float* Weq  = (const float*)d_in[12];
  const float* beq  = (const float*)d_in[13];
  const float* Wek  = (const float*)d_in[14];
  const float* bek  = (const float*)d_in[15];
  const float* Wo   = (const float*)d_in[16];
  const float* bo   = (const float*)d_in[17];
  float* out = (float*)d_out;

  float* Qm = (float*)d_ws;                                  // 384*256 f32
  float* Vm = Qm + LLEN*CDIM;                                // 384*256 f32
  unsigned short* QmH = (unsigned short*)(Vm + LLEN*CDIM);   // 384*256 bf16
  unsigned short* KmH = QmH + LLEN*CDIM;                     // 384*256 bf16
  unsigned short* Pp  = KmH + LLEN*CDIM;                     // 128*256
  unsigned short* Pq  = Pp  + DIN*CDIM;                      // 256*256
  unsigned short* Pk  = Pq  + CDIM*CDIM;
  unsigned short* PWq = Pk  + CDIM*CDIM;
  unsigned short* PWk = PWq + CDIM*CDIM;
  unsigned short* PWv = PWk + CDIM*CDIM;
  float* Sg     = (float*)(PWv + CDIM*CDIM);                 // 384*8*384 f32
  float* x2part = Sg + (size_t)LLEN*NH*LLEN;                 // 6*384*256 f32

  pack_w<<<dim3(176), dim3(256), 0, stream>>>(Wpre, Weq, Wek, Wq, Wk, Wv,
                                              Pp, Pq, Pk, PWq, PWk, PWv);
  qkv_mfma<<<dim3(6), dim3(256), 0, stream>>>(x3d, bq, bk, bv, PWq, PWk, PWv,
                                              Qm, Vm, QmH, KmH);
  qk_dots<<<dim3(36), dim3(256), 0, stream>>>(QmH, KmH, Sg);
  x3d_tiles<<<dim3(LLEN*6), dim3(256), 0, stream>>>(x2d, bpre, ln_g, ln_b, beq, bek,
                                                    Qm, Pp, Pq, Pk, Sg, x2part);
  finish<<<dim3(LLEN), dim3(256), 0, stream>>>(Sg, x2part, Vm, Wo, bo, out);
}

// Round 3
// 239.200 us; speedup vs baseline: 2.4756x; 1.1048x over previous
//
#include <hip/hip_runtime.h>
#include <hip/hip_bf16.h>

#define LLEN 384
#define CDIM 256
#define NH 8
#define HD 32
#define DIN 128
#define LN_EPS 1e-5f
#define SCL 0.17677669529663687f   // 1/sqrt(32)

typedef __attribute__((ext_vector_type(8))) short bh8;
typedef __attribute__((ext_vector_type(4))) float f32x4;
typedef __attribute__((ext_vector_type(4))) unsigned int u32x4;

__device__ __forceinline__ unsigned short f2bf(float f){
  unsigned int u = __float_as_uint(f);
  u += 0x7fffu + ((u >> 16) & 1u);
  return (unsigned short)(u >> 16);
}

// Packed tree-reduce: sum v[0..7] over the 16 lanes of a quad (lane bits 0-3).
// Returns: lane lm holds full sum of v[lm&7]  (index p = 4b2+2b1+b0).
__device__ __forceinline__ float pk_reduce8(const float* v, int lane){
  bool b0 = lane & 1, b1 = lane & 2, b2 = lane & 4;
  float r0 = (b0 ? v[1] : v[0]) + __shfl_xor(b0 ? v[0] : v[1], 1, 64);
  float r1 = (b0 ? v[3] : v[2]) + __shfl_xor(b0 ? v[2] : v[3], 1, 64);
  float r2 = (b0 ? v[5] : v[4]) + __shfl_xor(b0 ? v[4] : v[5], 1, 64);
  float r3 = (b0 ? v[7] : v[6]) + __shfl_xor(b0 ? v[6] : v[7], 1, 64);
  float s0 = (b1 ? r1 : r0) + __shfl_xor(b1 ? r0 : r1, 2, 64);
  float s1 = (b1 ? r3 : r2) + __shfl_xor(b1 ? r2 : r3, 2, 64);
  float t0 = (b2 ? s1 : s0) + __shfl_xor(b2 ? s0 : s1, 4, 64);
  return t0 + __shfl_xor(t0, 8, 64);
}

// ---------------------------------------------------------------------------
// Pack weights (fp32 row-major [K][N]) into bf16 MFMA B-fragment order.
// ---------------------------------------------------------------------------
__global__ __launch_bounds__(256) void pack_w(
    const float* __restrict__ Wpre, const float* __restrict__ Weq,
    const float* __restrict__ Wek,  const float* __restrict__ Wq,
    const float* __restrict__ Wk,   const float* __restrict__ Wv,
    unsigned short* __restrict__ Pp, unsigned short* __restrict__ Pq,
    unsigned short* __restrict__ Pk, unsigned short* __restrict__ PWq,
    unsigned short* __restrict__ PWk, unsigned short* __restrict__ PWv)
{
  int tid = blockIdx.x * 256 + threadIdx.x;   // 176 blocks * 256 = 45056
  const float* W; unsigned short* P; int base;
  if      (tid <  4096){ W = Wpre; P = Pp;  base = tid;         }
  else if (tid < 12288){ W = Weq;  P = Pq;  base = tid -  4096; }
  else if (tid < 20480){ W = Wek;  P = Pk;  base = tid - 12288; }
  else if (tid < 28672){ W = Wq;   P = PWq; base = tid - 20480; }
  else if (tid < 36864){ W = Wk;   P = PWk; base = tid - 28672; }
  else                 { W = Wv;   P = PWv; base = tid - 36864; }
  int l   = base & 63;
  int c   = (base >> 6) & 15;
  int kc  = base >> 10;
  int krow = kc*32 + (l >> 4)*8;
  int col  = c*16 + (l & 15);
  unsigned int wds[4];
  #pragma unroll
  for (int p = 0; p < 4; p++){
    unsigned short lo = f2bf(W[(size_t)(krow + 2*p    )*CDIM + col]);
    unsigned short hi = f2bf(W[(size_t)(krow + 2*p + 1)*CDIM + col]);
    wds[p] = (unsigned int)lo | ((unsigned int)hi << 16);
  }
  uint4 v; v.x = wds[0]; v.y = wds[1]; v.z = wds[2]; v.w = wds[3];
  *(uint4*)(P + (size_t)base*8) = v;
}

// ---------------------------------------------------------------------------
// qkv: 18 blocks (jb 0..5  x  m 0..2).
//  m=0: QmH (bf16 row-major) + QmT (fp32 transposed [c][j])
//  m=1: PKt  (K^T in MFMA B-frag layout, per head: kc==h, K=32)
//  m=2: Vm (fp32 row-major)
// ---------------------------------------------------------------------------
__global__ __launch_bounds__(256) void qkv_mfma(
    const float* __restrict__ x3d,
    const float* __restrict__ bq, const float* __restrict__ bk, const float* __restrict__ bv,
    const unsigned short* __restrict__ PWq, const unsigned short* __restrict__ PWk,
    const unsigned short* __restrict__ PWv,
    float* __restrict__ Vm, unsigned short* __restrict__ QmH,
    float* __restrict__ QmT, unsigned short* __restrict__ PKt)
{
  __shared__ __align__(16) unsigned short Xb[64*264];
  const int bx = blockIdx.x;
  const int jb = bx / 3, m = bx % 3;
  const int t  = threadIdx.x;
  const int w  = t >> 6, l = t & 63, q4 = l >> 4, lm = l & 15;
  const int wbase = w << 6;

  const float* src = x3d + (size_t)jb*64*CDIM;
  #pragma unroll
  for (int it = 0; it < 16; it++){
    int idx = it*256 + t;             // float4 index over 64x64
    int r = idx >> 6, k4 = (idx & 63) << 2;
    float4 v = *(const float4*)(src + (size_t)r*CDIM + k4);
    ushort4 b;
    b.x = f2bf(v.x); b.y = f2bf(v.y); b.z = f2bf(v.z); b.w = f2bf(v.w);
    *(ushort4*)(&Xb[r*264 + k4]) = b;
  }
  __syncthreads();

  const unsigned short* P = (m == 0) ? PWq : (m == 1) ? PWk : PWv;
  const float* bias       = (m == 0) ? bq  : (m == 1) ? bk  : bv;
  f32x4 acc[4][4];
  #pragma unroll
  for (int a = 0; a < 4; a++)
    #pragma unroll
    for (int b = 0; b < 4; b++){ f32x4 z = {0.f,0.f,0.f,0.f}; acc[a][b] = z; }
  #pragma unroll
  for (int kc = 0; kc < 8; kc++){
    bh8 af[4];
    #pragma unroll
    for (int rt = 0; rt < 4; rt++)
      af[rt] = *(const bh8*)(&Xb[(rt*16 + lm)*264 + kc*32 + q4*8]);
    #pragma unroll
    for (int ct = 0; ct < 4; ct++){
      bh8 bf = *(const bh8*)(P + ((size_t)(kc*16 + (w*4 + ct))*64 + l)*8);
      #pragma unroll
      for (int rt = 0; rt < 4; rt++)
        acc[rt][ct] = __builtin_amdgcn_mfma_f32_16x16x32_bf16(af[rt], bf, acc[rt][ct], 0, 0, 0);
    }
  }
  #pragma unroll
  for (int ct = 0; ct < 4; ct++){
    int c = wbase + ct*16 + lm;
    float bb = bias[c];
    #pragma unroll
    for (int rt = 0; rt < 4; rt++)
      #pragma unroll
      for (int rg = 0; rg < 4; rg++){
        int row = jb*64 + rt*16 + q4*4 + rg;
        float v = acc[rt][ct][rg] + bb;
        if (m == 0){
          QmH[(size_t)row*CDIM + c] = f2bf(v);
          QmT[(size_t)c*LLEN + row] = v;
        } else if (m == 1){
          int kc2 = c >> 5;            // head
          int jj2 = c & 7;
          int l2  = ((c >> 3) & 3)*16 + (row & 15);
          PKt[(((size_t)kc2*24 + (row >> 4))*64 + l2)*8 + jj2] = f2bf(v);
        } else {
          Vm[(size_t)row*CDIM + c] = v;
        }
      }
  }
}

// ---------------------------------------------------------------------------
// Main tile kernel: one block per (i, j-tile). 2304 blocks.
// Computes q.k term in-kernel via MFMA; writes final scores to Sg + x2 partials.
// ---------------------------------------------------------------------------
__global__ __launch_bounds__(256, 3) void x3d_tiles(
  const float* __restrict__ x2d,
  const float* __restrict__ bpre, const float* __restrict__ ln_g, const float* __restrict__ ln_b,
  const float* __restrict__ beq,  const float* __restrict__ bek,
  const float* __restrict__ QmT,  const unsigned short* __restrict__ QmH,
  const unsigned short* __restrict__ PKt,
  const unsigned short* __restrict__ Pp, const unsigned short* __restrict__ Pq,
  const unsigned short* __restrict__ Pk,
  float* __restrict__ Sg, float* __restrict__ x2part)
{
  __shared__ __align__(16) unsigned short EX[64*264];      // 33792 B
  __shared__ float rowstat[4][64][2];                      //  2048 B
  __shared__ float muS[64], istdS[64];                     //   512 B
  __shared__ float bpreS[CDIM], gS[CDIM], bSh[CDIM], beqS[CDIM], bekS[CDIM]; // 5120 B
  __shared__ float qk1S[NH*64];                            //  2048 B

  const int bx = blockIdx.x;
  const int i = bx / 6, jt = bx % 6, j0 = jt * 64;
  const int t = threadIdx.x;
  const int w = t >> 6, l = t & 63, q4 = l >> 4, lm = l & 15;
  const int wbase = w << 6;

  // ---- term1 via MFMA: qk1[h][j] = q_i(h).k_j(h); wave w does heads 2w,2w+1
  {
    #pragma unroll
    for (int hh = 0; hh < 2; hh++){
      int h = 2*w + hh;
      bh8 aq = *(const bh8*)(QmH + (size_t)i*CDIM + h*HD + q4*8);
      #pragma unroll
      for (int ct = 0; ct < 4; ct++){
        bh8 bf = *(const bh8*)(PKt + (((size_t)h*24 + (jt*4 + ct))*64 + l)*8);
        f32x4 z = {0.f,0.f,0.f,0.f};
        f32x4 a1 = __builtin_amdgcn_mfma_f32_16x16x32_bf16(aq, bf, z, 0, 0, 0);
        if (q4 == 0) qk1S[h*64 + ct*16 + lm] = a1[0];
      }
    }
  }

  bpreS[t] = bpre[t]; gS[t] = ln_g[t]; bSh[t] = ln_b[t];
  beqS[t]  = beq[t];  bekS[t] = bek[t];

  // ---- stage x2d tile (64 x 128) as bf16, stride 136 (non-temporal) ----
  {
    const float* src = x2d + ((size_t)i*LLEN + j0)*DIN;
    #pragma unroll
    for (int it = 0; it < 8; it++){
      int r  = it*8 + (t >> 5);
      int k4 = (t & 31)*4;
      u32x4 uv = __builtin_nontemporal_load((const u32x4*)(src + (size_t)r*DIN + k4));
      ushort4 b;
      b.x = f2bf(__uint_as_float(uv.x)); b.y = f2bf(__uint_as_float(uv.y));
      b.z = f2bf(__uint_as_float(uv.z)); b.w = f2bf(__uint_as_float(uv.w));
      *(ushort4*)(&EX[r*136 + k4]) = b;
    }
  }
  __syncthreads();

  // ---- GEMM1: Epre = X @ Wpre ----
  f32x4 acc[4][4];
  #pragma unroll
  for (int a = 0; a < 4; a++)
    #pragma unroll
    for (int b = 0; b < 4; b++){ f32x4 z = {0.f,0.f,0.f,0.f}; acc[a][b] = z; }
  #pragma unroll
  for (int kc = 0; kc < 4; kc++){
    bh8 af[4];
    #pragma unroll
    for (int rt = 0; rt < 4; rt++)
      af[rt] = *(const bh8*)(&EX[(rt*16 + lm)*136 + kc*32 + q4*8]);
    #pragma unroll
    for (int ct = 0; ct < 4; ct++){
      bh8 bf = *(const bh8*)(Pp + ((size_t)(kc*16 + (w*4 + ct))*64 + l)*8);
      #pragma unroll
      for (int rt = 0; rt < 4; rt++)
        acc[rt][ct] = __builtin_amdgcn_mfma_f32_16x16x32_bf16(af[rt], bf, acc[rt][ct], 0, 0, 0);
    }
  }

  // ---- + bpre, per-row LN stats via packed tree-reduce ----
  #pragma unroll
  for (int rt = 0; rt < 4; rt++){
    float v[8];   // v[2rg+0]=sum partial, v[2rg+1]=sq partial
    #pragma unroll
    for (int p = 0; p < 8; p++) v[p] = 0.f;
    #pragma unroll
    for (int ct = 0; ct < 4; ct++){
      float bb = bpreS[wbase + ct*16 + lm];
      #pragma unroll
      for (int rg = 0; rg < 4; rg++){
        float x = acc[rt][ct][rg] + bb;
        acc[rt][ct][rg] = x;
        v[2*rg]   += x;
        v[2*rg+1] += x*x;
      }
    }
    float red = pk_reduce8(v, lm);
    if (lm < 8){
      int p = lm;                       // p = 2rg+which
      rowstat[w][rt*16 + q4*4 + (p >> 1)][p & 1] = red;
    }
  }
  __syncthreads();
  if (t < 64){
    float s  = rowstat[0][t][0] + rowstat[1][t][0] + rowstat[2][t][0] + rowstat[3][t][0];
    float s2 = rowstat[0][t][1] + rowstat[1][t][1] + rowstat[2][t][1] + rowstat[3][t][1];
    float mu = s * (1.f/256.f);
    float var = s2 * (1.f/256.f) - mu*mu;
    muS[t] = mu;
    istdS[t] = rsqrtf(var + LN_EPS);
  }
  __syncthreads();

  // ---- LN + ReLU -> bf16 E tile (stride 264) ----
  #pragma unroll
  for (int rt = 0; rt < 4; rt++){
    #pragma unroll
    for (int rg = 0; rg < 4; rg++){
      int row = rt*16 + q4*4 + rg;
      float mu = muS[row], is = istdS[row];
      #pragma unroll
      for (int ct = 0; ct < 4; ct++){
        int c = wbase + ct*16 + lm;
        float v = (acc[rt][ct][rg] - mu)*is*gS[c] + bSh[c];
        v = fmaxf(v, 0.f);
        EX[row*264 + c] = f2bf(v);
      }
    }
  }
  __syncthreads();

  // ---- GEMM2: EFK = E @ Wek ----
  #pragma unroll
  for (int a = 0; a < 4; a++)
    #pragma unroll
    for (int b = 0; b < 4; b++){ f32x4 z = {0.f,0.f,0.f,0.f}; acc[a][b] = z; }
  #pragma unroll
  for (int kc = 0; kc < 8; kc++){
    bh8 af[4];
    #pragma unroll
    for (int rt = 0; rt < 4; rt++)
      af[rt] = *(const bh8*)(&EX[(rt*16 + lm)*264 + kc*32 + q4*8]);
    #pragma unroll
    for (int ct = 0; ct < 4; ct++){
      bh8 bf = *(const bh8*)(Pk + ((size_t)(kc*16 + (w*4 + ct))*64 + l)*8);
      #pragma unroll
      for (int rt = 0; rt < 4; rt++)
        acc[rt][ct] = __builtin_amdgcn_mfma_f32_16x16x32_bf16(af[rt], bf, acc[rt][ct], 0, 0, 0);
    }
  }

  // ---- scores: term2 packed-reduce + qk1 + scale; keep in screg ----
  float screg[4];
  #pragma unroll
  for (int rt = 0; rt < 4; rt++){
    float v[8];   // v[2rg+which]
    #pragma unroll
    for (int p = 0; p < 8; p++) v[p] = 0.f;
    #pragma unroll
    for (int ct = 0; ct < 4; ct++){
      int c = wbase + ct*16 + lm;
      float bek_ = bekS[c];
      float4 qv = *(const float4*)(QmT + (size_t)c*LLEN + j0 + rt*16 + q4*4);
      int wh = ct >> 1;
      v[0 + wh] += (acc[rt][ct][0] + bek_) * qv.x;
      v[2 + wh] += (acc[rt][ct][1] + bek_) * qv.y;
      v[4 + wh] += (acc[rt][ct][2] + bek_) * qv.z;
      v[6 + wh] += (acc[rt][ct][3] + bek_) * qv.w;
    }
    float red = pk_reduce8(v, lm);
    int p = lm & 7;                     // p = 2rg + which
    int jloc = rt*16 + q4*4 + (p >> 1);
    float sc = (red + qk1S[(2*w + (p & 1))*64 + jloc]) * SCL;
    screg[rt] = sc;
    if (lm < 8)
      Sg[((size_t)i*NH + 2*w + (p & 1))*LLEN + j0 + jloc] = sc;
  }

  // ---- GEMM3: EFQ = E @ Weq ----
  #pragma unroll
  for (int a = 0; a < 4; a++)
    #pragma unroll
    for (int b = 0; b < 4; b++){ f32x4 z = {0.f,0.f,0.f,0.f}; acc[a][b] = z; }
  #pragma unroll
  for (int kc = 0; kc < 8; kc++){
    bh8 af[4];
    #pragma unroll
    for (int rt = 0; rt < 4; rt++)
      af[rt] = *(const bh8*)(&EX[(rt*16 + lm)*264 + kc*32 + q4*8]);
    #pragma unroll
    for (int ct = 0; ct < 4; ct++){
      bh8 bf = *(const bh8*)(Pq + ((size_t)(kc*16 + (w*4 + ct))*64 + l)*8);
      #pragma unroll
      for (int rt = 0; rt < 4; rt++)
        acc[rt][ct] = __builtin_amdgcn_mfma_f32_16x16x32_bf16(af[rt], bf, acc[rt][ct], 0, 0, 0);
    }
  }

  // ---- x2 partials: x2[h,c] += s[h,j]*efq[j,c]  (pre-softmax scaled) ----
  float x2p[4] = {0.f, 0.f, 0.f, 0.f};
  float bq4[4];
  #pragma unroll
  for (int ct = 0; ct < 4; ct++) bq4[ct] = beqS[wbase + ct*16 + lm];
  #pragma unroll
  for (int rt = 0; rt < 4; rt++){
    // broadcast scores for this rt: s[rg][wh] from lane (l&48)|(2rg+wh)
    float sb[8];
    #pragma unroll
    for (int p = 0; p < 8; p++)
      sb[p] = __shfl(screg[rt], (l & 48) | p, 64);
    #pragma unroll
    for (int ct = 0; ct < 4; ct++){
      int wh = ct >> 1;
      #pragma unroll
      for (int rg = 0; rg < 4; rg++)
        x2p[ct] = fmaf(sb[2*rg + wh], acc[rt][ct][rg] + bq4[ct], x2p[ct]);
    }
  }
  // packed quad-reduce over lane bits 4,5: lane ends with ct = 2*b5+b4
  {
    bool b4 = l & 16, b5 = l & 32;
    float r0 = (b4 ? x2p[1] : x2p[0]) + __shfl_xor(b4 ? x2p[0] : x2p[1], 16, 64);
    float r1 = (b4 ? x2p[3] : x2p[2]) + __shfl_xor(b4 ? x2p[2] : x2p[3], 16, 64);
    float q  = (b5 ? r1 : r0) + __shfl_xor(b5 ? r0 : r1, 32, 64);
    int ctq = ((l >> 4) & 1) | (((l >> 5) & 1) << 1);
    x2part[((size_t)jt*LLEN + i)*CDIM + wbase + ctq*16 + lm] = q;
  }
}

// ---------------------------------------------------------------------------
// finish: softmax + x1 + x2 + out-proj. 384 blocks.
// ---------------------------------------------------------------------------
__global__ __launch_bounds__(256) void finish(
    const float* __restrict__ Sg, const float* __restrict__ x2part,
    const float* __restrict__ Vm, const float* __restrict__ Wo,
    const float* __restrict__ bo, float* __restrict__ out)
{
  __shared__ float scoresS[NH*LLEN];   // 12 KB
  __shared__ float xoutS[CDIM];
  const int i = blockIdx.x;
  const int t = threadIdx.x;

  #pragma unroll
  for (int it = 0; it < 3; it++)
    ((float4*)scoresS)[it*256 + t] = ((const float4*)(Sg + (size_t)i*NH*LLEN))[it*256 + t];
  __syncthreads();

  const int h = t >> 5;
  const int g32 = t & 31;
  float sv[12];
  float mx = -3.0e38f;
  #pragma unroll
  for (int it = 0; it < 12; it++){
    float s = scoresS[h*LLEN + it*32 + g32];
    sv[it] = s;
    mx = fmaxf(mx, s);
  }
  #pragma unroll
  for (int mk = 1; mk < 32; mk <<= 1) mx = fmaxf(mx, __shfl_xor(mx, mk, 64));
  float den = 0.f;
  #pragma unroll
  for (int it = 0; it < 12; it++){ float e = __expf(sv[it] - mx); sv[it] = e; den += e; }
  #pragma unroll
  for (int mk = 1; mk < 32; mk <<= 1) den += __shfl_xor(den, mk, 64);
  float rden = 1.f / den;
  #pragma unroll
  for (int it = 0; it < 12; it++) scoresS[h*LLEN + it*32 + g32] = sv[it]*rden;
  __syncthreads();

  // x1 with 4 independent accumulators
  float a0 = 0.f, a1 = 0.f, a2 = 0.f, a3 = 0.f;
  {
    const float* vp = Vm + t;
    const float* sp = scoresS + h*LLEN;
    #pragma unroll 4
    for (int j = 0; j < LLEN; j += 4){
      a0 = fmaf(sp[j+0], vp[(size_t)(j+0)*CDIM], a0);
      a1 = fmaf(sp[j+1], vp[(size_t)(j+1)*CDIM], a1);
      a2 = fmaf(sp[j+2], vp[(size_t)(j+2)*CDIM], a2);
      a3 = fmaf(sp[j+3], vp[(size_t)(j+3)*CDIM], a3);
    }
  }
  float x2v = 0.f;
  #pragma unroll
  for (int jt = 0; jt < 6; jt++)
    x2v += x2part[((size_t)jt*LLEN + i)*CDIM + t];
  xoutS[t] = (a0 + a1) + (a2 + a3) + x2v;
  __syncthreads();

  float b0a = bo[t], b1a = 0.f, b2a = 0.f, b3a = 0.f;
  #pragma unroll 4
  for (int c = 0; c < CDIM; c += 4){
    b0a = fmaf(xoutS[c+0], Wo[(size_t)(c+0)*CDIM + t], b0a);
    b1a = fmaf(xoutS[c+1], Wo[(size_t)(c+1)*CDIM + t], b1a);
    b2a = fmaf(xoutS[c+2], Wo[(size_t)(c+2)*CDIM + t], b2a);
    b3a = fmaf(xoutS[c+3], Wo[(size_t)(c+3)*CDIM + t], b3a);
  }
  out[(size_t)i*CDIM + t] = (b0a + b1a) + (b2a + b3a);
}

// ---------------------------------------------------------------------------
extern "C" void kernel_launch(void* const* d_in, const int* in_sizes, int n_in,
                              void* d_out, int out_size, void* d_ws, size_t ws_size,
                              hipStream_t stream)
{
  const float* x2d  = (const float*)d_in[0];
  const float* x3d  = (const float*)d_in[1];
  const float* Wq   = (const float*)d_in[2];
  const float* bq   = (const float*)d_in[3];
  const float* Wk   = (const float*)d_in[4];
  const float* bk   = (const float*)d_in[5];
  const float* Wv   = (const float*)d_in[6];
  const float* bv   = (const float*)d_in[7];
  const float* Wpre = (const float*)d_in[8];
  const float* bpre = (const float*)d_in[9];
  const float* ln_g = (const float*)d_in[10];
  const float* ln_b = (const float*)d_in[11];
  const float* Weq  = (const float*)d_in[12];
  const float* beq  = (const float*)d_in[13];
  const float* Wek  = (const float*)d_in[14];
  const float* bek  = (const float*)d_in[15];
  const float* Wo   = (const float*)d_in[16];
  const float* bo   = (const float*)d_in[17];
  float* out = (float*)d_out;

  float* Vm  = (float*)d_ws;                                 // 384*256 f32
  float* QmT = Vm + LLEN*CDIM;                               // 256*384 f32
  unsigned short* QmH = (unsigned short*)(QmT + CDIM*LLEN);  // 384*256 bf16
  unsigned short* PKt = QmH + LLEN*CDIM;                     // 8*24*64*8 bf16
  unsigned short* Pp  = PKt + LLEN*CDIM;                     // 128*256
  unsigned short* Pq  = Pp  + DIN*CDIM;                      // 256*256
  unsigned short* Pk  = Pq  + CDIM*CDIM;
  unsigned short* PWq = Pk  + CDIM*CDIM;
  unsigned short* PWk = PWq + CDIM*CDIM;
  unsigned short* PWv = PWk + CDIM*CDIM;
  float* Sg     = (float*)(PWv + CDIM*CDIM);                 // 384*8*384 f32
  float* x2part = Sg + (size_t)LLEN*NH*LLEN;                 // 6*384*256 f32

  pack_w<<<dim3(176), dim3(256), 0, stream>>>(Wpre, Weq, Wek, Wq, Wk, Wv,
                                              Pp, Pq, Pk, PWq, PWk, PWv);
  qkv_mfma<<<dim3(18), dim3(256), 0, stream>>>(x3d, bq, bk, bv, PWq, PWk, PWv,
                                               Vm, QmH, QmT, PKt);
  x3d_tiles<<<dim3(LLEN*6), dim3(256), 0, stream>>>(x2d, bpre, ln_g, ln_b, beq, bek,
                                                    QmT, QmH, PKt, Pp, Pq, Pk, Sg, x2part);
  finish<<<dim3(LLEN), dim3(256), 0, stream>>>(Sg, x2part, Vm, Wo, bo, out);
}